// Round 1
// baseline (177.900 us; speedup 1.0000x reference)
//
#include <hip/hip_runtime.h>

// MaxUnpool2D, ENet decoder shape:
//   input_pool [B=8, H=128, W=128, C=64] f32
//   pool_mask  [B, H, W, C] i32 -- flat per-batch index (ho*WOUT + wo)*C + c
//   out        [B, HOUT=256, WOUT=256, C=64] f32, zeros except masked positions.
//
// Inverted to a GATHER: every output element (b,ho,wo,c) reads the unique
// input cell (b, ho>>1, wo>>1, c) and keeps the value only if the mask picked
// exactly this (ho,wo). Fuses zero-init + scatter, coalesced, no atomics.

#define Bsz   8
#define Hdim  128
#define Wdim  128
#define Cdim  64
#define HOUT  256
#define WOUT  256

__global__ __launch_bounds__(256) void maxunpool_gather(
    const float4* __restrict__ x,     // [B*H*W*C/4]
    const int4*   __restrict__ mask,  // [B*H*W*C/4]
    float4*       __restrict__ out)   // [B*HOUT*WOUT*C/4]
{
    constexpr int CV = Cdim / 4;  // 16 float4 per pixel
    // tid indexes [B, HOUT, WOUT, CV]
    unsigned int tid = blockIdx.x * blockDim.x + threadIdx.x;

    int c4   = tid & (CV - 1);            // which float4 within channels
    unsigned int r1 = tid >> 4;           // (b*HOUT + ho)*WOUT + wo
    int wo   = r1 & (WOUT - 1);
    unsigned int r2 = r1 >> 8;
    int ho   = r2 & (HOUT - 1);
    int b    = r2 >> 8;

    int h = ho >> 1;
    int w = wo >> 1;

    unsigned int in_vec = ((unsigned int)(b * Hdim + h) * Wdim + w) * CV + c4;

    int4   m = mask[in_vec];
    float4 v = x[in_vec];

    // expected flat index (within batch) for channels c4*4 .. c4*4+3
    int base = (ho * WOUT + wo) * Cdim + c4 * 4;

    float4 r;
    r.x = (m.x == base + 0) ? v.x : 0.0f;
    r.y = (m.y == base + 1) ? v.y : 0.0f;
    r.z = (m.z == base + 2) ? v.z : 0.0f;
    r.w = (m.w == base + 3) ? v.w : 0.0f;

    out[tid] = r;
}

extern "C" void kernel_launch(void* const* d_in, const int* in_sizes, int n_in,
                              void* d_out, int out_size, void* d_ws, size_t ws_size,
                              hipStream_t stream) {
    const float4* x    = (const float4*)d_in[0];
    const int4*   mask = (const int4*)d_in[1];
    float4*       out  = (float4*)d_out;

    // out_size = 8*256*256*64 = 33,554,432 elements -> /4 = 8,388,608 threads
    const int n_vec = out_size / 4;
    const int block = 256;
    const int grid  = n_vec / block;  // 32768, exact

    maxunpool_gather<<<grid, block, 0, stream>>>(x, mask, out);
}